// Round 15
// baseline (472.322 us; speedup 1.0000x reference)
//
#include <hip/hip_runtime.h>
#include <hip/hip_bf16.h>

// AttentionForQuantizer: q/k/v proj + RMSNorm + logits(32768x4096) + argmax + gather.
// R15: NODE FUSION 4->3 — rmsnorm absorbed into the projection GEMM, bit-exactly.
// Each gemm block now computes FULL 256-wide rows as two sequential 128-col halves
// (per-element FMA chain order unchanged -> qf/kf/vf bit-identical to R14), then after
// __syncthreads() runs the rmsnorm_rows body VERBATIM on its own 128 rows (same loads
// of same bits, same fmaf/butterfly/rsqrt order -> normed qf/kf and qb/kb bit-identical
// -> logits/Tmax/candidates/dots/idx provably unchanged; canary: absmax == 0.03125).
// Rationale: R12 measured G~21us/node (launch + inter-kernel L2 release); removing the
// rmsnorm node saves G plus overlaps the norm work into the gemm dispatch.
// mfma_logits / refine byte-identical to R14 (passed).

#define NTOK 32768
#define NCODE 4096
#define DIM 256

typedef __bf16 bf16x8 __attribute__((ext_vector_type(8)));
typedef float f32x4 __attribute__((ext_vector_type(4)));

__device__ __forceinline__ void nt_store4(const float4& v, float* p) {
    f32x4 w; w[0] = v.x; w[1] = v.y; w[2] = v.z; w[3] = v.w;
    __builtin_nontemporal_store(w, (f32x4*)p);
}

// ---------------- fused fp32 GEMMs + RMSNorm: k, v, q in one dispatch ----------------
// Grid 320 (1-D): bx<32 -> k (norm), bx<64 -> v (no norm), else q (norm).
// Per block: 128 rows x 256 cols via two 128-col halves; K-loop body identical to
// R3..R14 (same FMA order per element -> bit-identical raw y). Then in-kernel rmsnorm
// (verbatim rmsnorm_rows ops) on the block's own rows, reading raw y back via L2.
__global__ __launch_bounds__(256, 2)
void gemm3_norm(const float* __restrict__ hs, const float* __restrict__ cb,
                const float* __restrict__ wq, const float* __restrict__ bq,
                const float* __restrict__ wk, const float* __restrict__ bk,
                const float* __restrict__ wv, const float* __restrict__ bv,
                const float* __restrict__ gq, const float* __restrict__ gk,
                float* __restrict__ qf, float* __restrict__ kf, float* __restrict__ vf,
                __hip_bfloat16* __restrict__ qb16, __hip_bfloat16* __restrict__ kb16)
{
    __shared__ __align__(16) float Xs[32][132];  // [kk][m], padded
    __shared__ __align__(16) float Ws[32][132];  // [kk][n], padded
    const int t  = threadIdx.x;
    const int tm = t >> 4;         // 0..15
    const int tn = t & 15;         // 0..15

    const int bx = blockIdx.x;
    const float* X; const float* W; const float* bias; float* Y; int mb;
    const float* g = nullptr; __hip_bfloat16* Yb = nullptr; bool donorm;
    if (bx < 32)      { X = cb; W = wk; bias = bk; Y = kf; mb = bx * 128;        g = gk; Yb = kb16; donorm = true;  }
    else if (bx < 64) { X = cb; W = wv; bias = bv; Y = vf; mb = (bx - 32) * 128; donorm = false; }
    else              { X = hs; W = wq; bias = bq; Y = qf; mb = (bx - 64) * 128; g = gq; Yb = qb16; donorm = true;  }

    const int sxm = t >> 1;          // X staging: row 0..127
    const int sxh = (t & 1) * 16;    // X staging: k-half base
    const int swk = t >> 3;          // W staging: kk 0..31
    const int swc = (t & 7) * 16;    // W staging: col base

    #pragma unroll 1
    for (int h = 0; h < 2; ++h) {
        const int nb = h * 128;

        float acc[8][8];
        #pragma unroll
        for (int i = 0; i < 8; ++i)
            #pragma unroll
            for (int j = 0; j < 8; ++j) acc[i][j] = 0.f;

        for (int kb = 0; kb < 256; kb += 32) {
            float4 xv[4], wv4[4];
            #pragma unroll
            for (int i = 0; i < 4; ++i) {
                xv[i]  = *(const float4*)&X[(size_t)(mb + sxm) * 256 + kb + sxh + 4 * i];
                wv4[i] = *(const float4*)&W[(size_t)(kb + swk) * 256 + nb + swc + 4 * i];
            }
            __syncthreads();  // previous iteration's (or prior half's) LDS reads done
            #pragma unroll
            for (int i = 0; i < 4; ++i) {
                Xs[sxh + 4*i + 0][sxm] = xv[i].x;
                Xs[sxh + 4*i + 1][sxm] = xv[i].y;
                Xs[sxh + 4*i + 2][sxm] = xv[i].z;
                Xs[sxh + 4*i + 3][sxm] = xv[i].w;
                *(float4*)&Ws[swk][swc + 4*i] = wv4[i];
            }
            __syncthreads();
            #pragma unroll 8
            for (int kk = 0; kk < 32; ++kk) {
                float4 a0 = *(const float4*)&Xs[kk][tm*8];
                float4 a1 = *(const float4*)&Xs[kk][tm*8 + 4];
                float4 b0 = *(const float4*)&Ws[kk][tn*8];
                float4 b1 = *(const float4*)&Ws[kk][tn*8 + 4];
                float av[8] = {a0.x,a0.y,a0.z,a0.w,a1.x,a1.y,a1.z,a1.w};
                float bw[8] = {b0.x,b0.y,b0.z,b0.w,b1.x,b1.y,b1.z,b1.w};
                #pragma unroll
                for (int i = 0; i < 8; ++i)
                    #pragma unroll
                    for (int j = 0; j < 8; ++j)
                        acc[i][j] = fmaf(av[i], bw[j], acc[i][j]);
            }
        }

        float4 bb0 = *(const float4*)&bias[nb + tn*8];
        float4 bb1 = *(const float4*)&bias[nb + tn*8 + 4];
        float bb[8] = {bb0.x,bb0.y,bb0.z,bb0.w,bb1.x,bb1.y,bb1.z,bb1.w};
        #pragma unroll
        for (int i = 0; i < 8; ++i) {
            const size_t row = (size_t)(mb + tm*8 + i);
            float4 o0 = {acc[i][0]+bb[0], acc[i][1]+bb[1], acc[i][2]+bb[2], acc[i][3]+bb[3]};
            float4 o1 = {acc[i][4]+bb[4], acc[i][5]+bb[5], acc[i][6]+bb[6], acc[i][7]+bb[7]};
            *(float4*)&Y[row*256 + nb + tn*8]     = o0;   // raw y (cached: read back below)
            *(float4*)&Y[row*256 + nb + tn*8 + 4] = o1;
        }
    }

    if (donorm) {
        __syncthreads();   // raw-y stores drained & visible block-wide via L2
        const int lane = t & 63;
        const int w    = t >> 6;
        #pragma unroll 1
        for (int rr = 0; rr < 32; ++rr) {
            const size_t row = (size_t)mb + rr*4 + w;
            // ---- verbatim rmsnorm_rows body (bit-identical sequence) ----
            float4 x = *(const float4*)&Y[row*256 + lane*4];
            float ssq = fmaf(x.x, x.x, fmaf(x.y, x.y, fmaf(x.z, x.z, x.w * x.w)));
            #pragma unroll
            for (int o = 1; o < 64; o <<= 1) ssq += __shfl_xor(ssq, o, 64);
            const float r = 1.0f / sqrtf(ssq * (1.0f/256.0f) + 1e-5f);
            float4 gg = *(const float4*)&g[lane*4];
            float y0 = (x.x*r)*gg.x, y1 = (x.y*r)*gg.y, y2 = (x.z*r)*gg.z, y3 = (x.w*r)*gg.w;
            float4 y = {y0, y1, y2, y3};
            *(float4*)&Y[row*256 + lane*4] = y;
            __hip_bfloat16 h0 = __float2bfloat16(y0), h1 = __float2bfloat16(y1);
            __hip_bfloat16 h2 = __float2bfloat16(y2), h3 = __float2bfloat16(y3);
            ushort4 p;
            p.x = *(unsigned short*)&h0; p.y = *(unsigned short*)&h1;
            p.z = *(unsigned short*)&h2; p.w = *(unsigned short*)&h3;
            ((ushort4*)Yb)[row*64 + lane] = p;
        }
    }
}

// ---------------- bf16 MFMA logits: Out[32768][4096] = fp32(clamp(Q @ K^T * 1/16)) ----
// Byte-identical to R14 (passed): m97 loop, both-sides LDS swizzle, LDS-bounce epilogue
// with NONTEMPORAL logits stores, Tmax emission, lb(256,4), XCD-chunked grid.
__device__ __forceinline__ void load_lds16(const void* g, void* l) {
    __builtin_amdgcn_global_load_lds((const __attribute__((address_space(1))) unsigned int*)g,
                                     (__attribute__((address_space(3))) unsigned int*)l, 16, 0, 0);
}

__global__ __launch_bounds__(256, 4)
void mfma_logits(const __hip_bfloat16* __restrict__ Qb, const __hip_bfloat16* __restrict__ Kb,
                 float* __restrict__ Out, float* __restrict__ Tmax)
{
    __shared__ __align__(16) char smem[33792];
    __hip_bfloat16* Asm = (__hip_bfloat16*)smem;            // [128 rows][64 k] bf16, 16KB
    __hip_bfloat16* Bsm = (__hip_bfloat16*)(smem + 16384);  // [128 rows][64 k] bf16, 16KB
    float*          Eps = (float*)smem;                     // [64 rows][128 cols] fp32, 32KB
    float*          Pmax = (float*)(smem + 32768);          // [128 rows][2 halves], 1KB

    const int t    = threadIdx.x;
    const int lane = t & 63;
    const int w    = t >> 6;
    const int wm = w >> 1, wn = w & 1;      // 2x2 wave grid of 64x64 quadrants

    const int bid = blockIdx.x;
    const int xcd = bid & 7;
    const int cid = bid >> 3;                // 0..1023
    const int mb  = (xcd * 32 + (cid & 31)) * 128;
    const int ctl = cid >> 5;                // col-tile 0..31
    const int nb  = ctl * 128;

    const int grow   = t >> 3;                       // + i*32 per issue
    const int gslot  = (t & 7) ^ ((t >> 3) & 7);
    const __hip_bfloat16* gA = Qb + (size_t)(mb + grow) * 256 + gslot * 8;
    const __hip_bfloat16* gB = Kb + (size_t)(nb + grow) * 256 + gslot * 8;
    __hip_bfloat16* lA = &Asm[w * 512];              // + i*2048 per issue (bf16 elems)
    __hip_bfloat16* lB = &Bsm[w * 512];

    const int fr = lane & 15;
    const int kq = lane >> 4;
    const int rswz = lane & 7;                       // row&7 for all our fragment rows
    const int ra0 = (wm * 64 + fr) * 64;             // A base elem offset (row*64)
    const int rb0 = (wn * 64 + fr) * 64;

    f32x4 acc[4][4];
    #pragma unroll
    for (int mi = 0; mi < 4; ++mi)
        #pragma unroll
        for (int ni = 0; ni < 4; ++ni) {
            acc[mi][ni][0] = 0.f; acc[mi][ni][1] = 0.f;
            acc[mi][ni][2] = 0.f; acc[mi][ni][3] = 0.f;
        }

    for (int ks = 0; ks < 4; ++ks) {
        const int k0 = ks * 64;
        #pragma unroll
        for (int i = 0; i < 4; ++i) {
            load_lds16(gA + (size_t)i * 32 * 256 + k0, lA + i * 2048);
            load_lds16(gB + (size_t)i * 32 * 256 + k0, lB + i * 2048);
        }
        __syncthreads();   // compiler drains vmcnt(0) before s_barrier [m97 evidence]

        #pragma unroll
        for (int kh = 0; kh < 2; ++kh) {            // ascending k == R4..R14 order
            bf16x8 af[4], bg[4];
            #pragma unroll
            for (int mi = 0; mi < 4; ++mi)
                af[mi] = *(const bf16x8*)&Asm[ra0 + mi*16*64 + (((kh<<2) + kq) ^ rswz) * 8];
            #pragma unroll
            for (int ni = 0; ni < 4; ++ni)
                bg[ni] = *(const bf16x8*)&Bsm[rb0 + ni*16*64 + (((kh<<2) + kq) ^ rswz) * 8];
            #pragma unroll
            for (int mi = 0; mi < 4; ++mi)
                #pragma unroll
                for (int ni = 0; ni < 4; ++ni)
                    acc[mi][ni] = __builtin_amdgcn_mfma_f32_16x16x32_bf16(
                        af[mi], bg[ni], acc[mi][ni], 0, 0, 0);
        }
        __syncthreads();   // LDS reads done before next K-step overwrites / epilogue
    }

    // ---- per-row partial maxima from acc regs (row = wm*64+mi*16+(lane>>4)*4+j) ----
    #pragma unroll
    for (int mi = 0; mi < 4; ++mi)
        #pragma unroll
        for (int j = 0; j < 4; ++j) {
            float mx = fmaxf(fmaxf(acc[mi][0][j], acc[mi][1][j]),
                             fmaxf(acc[mi][2][j], acc[mi][3][j]));
            #pragma unroll
            for (int o = 1; o < 16; o <<= 1) mx = fmaxf(mx, __shfl_xor(mx, o, 64));
            if ((lane & 15) == 0)
                Pmax[(wm*64 + mi*16 + (lane>>4)*4 + j)*2 + wn] = mx;
        }

    // ---- epilogue: LDS bounce -> coalesced full-row dwordx4 NONTEMPORAL stores ----
    const int cr = (lane >> 4) * 4;
    const int cc = lane & 15;
    #pragma unroll
    for (int c = 0; c < 2; ++c) {                    // chunk: rows [c*64, c*64+64)
        if (wm == c) {
            #pragma unroll
            for (int mi = 0; mi < 4; ++mi)
                #pragma unroll
                for (int ni = 0; ni < 4; ++ni) {
                    const int lrow = mi*16 + cr;                  // 0..63 within chunk
                    const int lcol = wn*64 + ni*16 + cc;          // 0..127
                    #pragma unroll
                    for (int j = 0; j < 4; ++j) {
                        float v = acc[mi][ni][j] * 0.0625f;
                        v = fminf(fmaxf(v, -16.0f), 16.0f);
                        Eps[(lrow + j) * 128 + lcol] = v;
                    }
                }
        }
        __syncthreads();   // bounce tile (and, first pass, Pmax) complete
        #pragma unroll
        for (int it = 0; it < 8; ++it) {
            const int p   = it * 1024 + t * 4;       // linear word index in [64][128]
            const int row = p >> 7;
            const int col = p & 127;
            float4 v = *(const float4*)&Eps[p];
            nt_store4(v, &Out[(size_t)(mb + c*64 + row) * 4096 + nb + col]);
        }
        __syncthreads();   // chunk read done before next chunk overwrites
    }

    // ---- Tmax: max is monotone under clamp(0.0625*x) -> equals max of stored values.
    if (t < 128) {
        float raw = fmaxf(Pmax[t*2], Pmax[t*2 + 1]);
        float v = raw * 0.0625f;
        v = fminf(fmaxf(v, -16.0f), 16.0f);
        Tmax[(size_t)(mb + t) * 32 + ctl] = v;
    }
}

// ---------------- FROZEN canonical fp32 dot (argmax determinism anchor) ----------------
// DO NOT change the summation structure. R3..R14 PASSED with this exact sequence.
__device__ __forceinline__ float dot256_f32(const float* __restrict__ a, const float* __restrict__ b)
{
    float s0 = 0.f, s1 = 0.f, s2 = 0.f, s3 = 0.f;
    #pragma unroll 8
    for (int j = 0; j < 64; ++j) {
        float4 x = ((const float4*)a)[j];
        float4 y = ((const float4*)b)[j];
        s0 = fmaf(x.x, y.x, s0);
        s1 = fmaf(x.y, y.y, s1);
        s2 = fmaf(x.z, y.z, s2);
        s3 = fmaf(x.w, y.w, s3);
    }
    return (s0 + s1) + (s2 + s3);
}

// ---------------- refine (fast): Tmax-pruned candidate scan + frozen dots ----------------
// Byte-identical to R14 (passed): nt stores for idx/z_q/z_q_2; Qf aliases Zq (reads
// complete before the aliased overwrite via the bi data dependence).
__global__ __launch_bounds__(256)
void refine_argmax_fast(const float* __restrict__ L, const float* __restrict__ Tmax,
                        const float* __restrict__ Qf, const float* __restrict__ Kf,
                        const float* __restrict__ Vf, float* __restrict__ OutIdx,
                        float* __restrict__ Zq, float* __restrict__ Zq2)
{
    __shared__ int cnt[4];
    __shared__ int list[4][256];
    const int lane = threadIdx.x & 63;
    const int w    = threadIdx.x >> 6;
    const size_t row = (size_t)blockIdx.x * 4 + w;

    // phase 1: row max from 32 tile maxima
    float tm = (lane < 32) ? Tmax[row * 32 + lane] : -INFINITY;
    float gmax = tm;
    #pragma unroll
    for (int o = 1; o < 64; o <<= 1) gmax = fmaxf(gmax, __shfl_xor(gmax, o, 64));
    const float thr = gmax - 0.5f;

    if (lane == 0) cnt[w] = 0;
    __syncthreads();   // unconditional

    // phase 2: scan ONLY candidate tiles (512B each, float2/lane coalesced)
    for (int tile = 0; tile < 32; ++tile) {
        const float tmt = __shfl(tm, tile, 64);
        if (tmt >= thr) {
            const float2 v2 = *(const float2*)&L[row * 4096 + tile * 128 + lane * 2];
            if (v2.x >= thr) {
                int slot = atomicAdd(&cnt[w], 1);
                if (slot < 256) list[w][slot] = tile*128 + lane*2;
            }
            if (v2.y >= thr) {
                int slot = atomicAdd(&cnt[w], 1);
                if (slot < 256) list[w][slot] = tile*128 + lane*2 + 1;
            }
        }
    }
    __syncthreads();   // unconditional

    // phase 3: one candidate per lane, all dots in ONE exec pass
    int m = cnt[w]; if (m > 256) m = 256;
    float bv = -INFINITY;
    int   bi = 0x7fffffff;
    const float* qrow = Qf + row * 256;
    for (int base = 0; base < m; base += 64) {
        const int ci = base + lane;
        if (ci < m) {
            const int c = list[w][ci];
            float rv = dot256_f32(qrow, Kf + (size_t)c * 256) * 0.0625f;
            if (rv > bv || (rv == bv && c < bi)) { bv = rv; bi = c; }
        }
    }
    #pragma unroll
    for (int o = 1; o < 64; o <<= 1) {
        float ov = __shfl_xor(bv, o, 64);
        int   oi = __shfl_xor(bi, o, 64);
        if (ov > bv || (ov == bv && oi < bi)) { bv = ov; bi = oi; }
    }

    if (bi < 0) bi = 0;
    if (bi > 4095) bi = 4095;

    if (lane == 0) __builtin_nontemporal_store((float)bi, &OutIdx[row]);

    float4 vv = ((const float4*)(Vf + (size_t)bi * 256))[lane];
    nt_store4(vv, (float*)&((float4*)Zq)[row*64 + lane]);
    nt_store4(vv, (float*)&((float4*)Zq2)[row*64 + lane]);
}

extern "C" void kernel_launch(void* const* d_in, const int* in_sizes, int n_in,
                              void* d_out, int out_size, void* d_ws, size_t ws_size,
                              hipStream_t stream)
{
    (void)in_sizes; (void)n_in; (void)out_size;
    const float* hs = (const float*)d_in[0];
    const float* cb = (const float*)d_in[1];
    const float* wq = (const float*)d_in[2];
    const float* bq = (const float*)d_in[3];
    const float* wk = (const float*)d_in[4];
    const float* bk = (const float*)d_in[5];
    const float* wv = (const float*)d_in[6];
    const float* bv = (const float*)d_in[7];
    const float* gq = (const float*)d_in[8];
    const float* gk = (const float*)d_in[9];
    float* out = (float*)d_out;   // fp32: reference outputs are fp32/int32

    if (ws_size < 31457280u) return;  // need 30MB scratch

    // d_out layout (floats): logits @0 [32768*4096], idx @134217728 [32768],
    // z_q @134250496 [32768*256], z_q_2 @142639104 [32768*256].
    float* qf = out + 134250496ull;   // q lives in the z_q region until the FINAL refine store

    char* ws = (char*)d_ws;
    float* kf = (float*)ws;                                   //  4 MB: k raw -> k_norm (in place)
    float* vf = (float*)(ws + 4194304);                       //  4 MB: v
    __hip_bfloat16* qb = (__hip_bfloat16*)(ws + 8388608);     // 16 MB: q_norm bf16
    __hip_bfloat16* kb = (__hip_bfloat16*)(ws + 25165824);    //  2 MB: k_norm bf16
    float* tmax = (float*)(ws + 27262976);                    //  4 MB: per-tile row max

    gemm3_norm<<<320, 256, 0, stream>>>(hs, cb, wq, bq, wk, bk, wv, bv, gq, gk,
                                        qf, kf, vf, qb, kb);
    mfma_logits<<<8192, 256, 0, stream>>>(qb, kb, out, tmax);
    refine_argmax_fast<<<8192, 256, 0, stream>>>(out, tmax, qf, kf, vf,
        out + 134217728ull,   // idx
        out + 134250496ull,   // z_q   (aliases qf by design)
        out + 142639104ull);  // z_q_2
}

// Round 16
// 455.369 us; speedup vs baseline: 1.0372x; 1.0372x over previous
//
#include <hip/hip_runtime.h>
#include <hip/hip_bf16.h>

// AttentionForQuantizer: q/k/v proj + RMSNorm + logits(32768x4096) + argmax + gather.
// R16: R15 fusion kept, SHAPE fixed. R15 regressed (+31us) because 320 blocks x two
// sequential 128-col halves halved front-end parallelism. Now: 64-row x 256-col tiles,
// grid 640 (k:64, v:64, q:512), ONE K-loop per block, full rows per block -> verbatim
// in-kernel rmsnorm tail (R15 proved the store->barrier->reload pattern correct).
// Bit-exactness: each output element is a single fmaf chain over ascending k + one
// bias add — invariant to thread/block mapping; staged bits identical -> qf/kf/vf,
// qb/kb, logits, Tmax, candidates, frozen dots, idx all bit-identical to R14 (passed).
// Canary: absmax == 0.03125. mfma_logits / refine byte-identical to R14.

#define NTOK 32768
#define NCODE 4096
#define DIM 256

typedef __bf16 bf16x8 __attribute__((ext_vector_type(8)));
typedef float f32x4 __attribute__((ext_vector_type(4)));

__device__ __forceinline__ void nt_store4(const float4& v, float* p) {
    f32x4 w; w[0] = v.x; w[1] = v.y; w[2] = v.z; w[3] = v.w;
    __builtin_nontemporal_store(w, (f32x4*)p);
}

// ------------- fused fp32 GEMMs + RMSNorm: 64x256 tile per block, grid 640 -------------
// bx<64 -> k (norm), bx<128 -> v (no norm), else q (norm). Threads: tm=t>>5 (8 row
// groups of 8), tn=t&31 (32 col groups of 8). Per-element FMA chain order unchanged.
__global__ __launch_bounds__(256, 2)
void gemm3_norm(const float* __restrict__ hs, const float* __restrict__ cb,
                const float* __restrict__ wq, const float* __restrict__ bq,
                const float* __restrict__ wk, const float* __restrict__ bk,
                const float* __restrict__ wv, const float* __restrict__ bv,
                const float* __restrict__ gq, const float* __restrict__ gk,
                float* __restrict__ qf, float* __restrict__ kf, float* __restrict__ vf,
                __hip_bfloat16* __restrict__ qb16, __hip_bfloat16* __restrict__ kb16)
{
    __shared__ __align__(16) float Xs[32][68];   // [kk][row 0..63], padded
    __shared__ __align__(16) float Ws[32][260];  // [kk][col 0..255], padded
    const int t  = threadIdx.x;
    const int tm = t >> 5;         // 0..7   row group
    const int tn = t & 31;         // 0..31  col group

    const int bx = blockIdx.x;
    const float* X; const float* W; const float* bias; float* Y; int mb;
    const float* g = nullptr; __hip_bfloat16* Yb = nullptr; bool donorm;
    if (bx < 64)       { X = cb; W = wk; bias = bk; Y = kf; mb = bx * 64;         g = gk; Yb = kb16; donorm = true;  }
    else if (bx < 128) { X = cb; W = wv; bias = bv; Y = vf; mb = (bx - 64) * 64;  donorm = false; }
    else               { X = hs; W = wq; bias = bq; Y = qf; mb = (bx - 128) * 64; g = gq; Yb = qb16; donorm = true;  }

    float acc[8][8];
    #pragma unroll
    for (int i = 0; i < 8; ++i)
        #pragma unroll
        for (int j = 0; j < 8; ++j) acc[i][j] = 0.f;

    const int sxr = t >> 2;          // X staging: row 0..63
    const int sxh = (t & 3) * 8;     // X staging: k offset 0,8,16,24
    const int swk = t >> 3;          // W staging: kk 0..31
    const int swc = (t & 7) * 32;    // W staging: col base 0..224

    for (int kb = 0; kb < 256; kb += 32) {
        float4 xv[2], wv4[8];
        #pragma unroll
        for (int i = 0; i < 2; ++i)
            xv[i] = *(const float4*)&X[(size_t)(mb + sxr) * 256 + kb + sxh + 4 * i];
        #pragma unroll
        for (int i = 0; i < 8; ++i)
            wv4[i] = *(const float4*)&W[(size_t)(kb + swk) * 256 + swc + 4 * i];
        __syncthreads();  // previous iteration's LDS reads done before overwrite
        #pragma unroll
        for (int i = 0; i < 2; ++i) {
            Xs[sxh + 4*i + 0][sxr] = xv[i].x;
            Xs[sxh + 4*i + 1][sxr] = xv[i].y;
            Xs[sxh + 4*i + 2][sxr] = xv[i].z;
            Xs[sxh + 4*i + 3][sxr] = xv[i].w;
        }
        #pragma unroll
        for (int i = 0; i < 8; ++i)
            *(float4*)&Ws[swk][swc + 4*i] = wv4[i];
        __syncthreads();
        #pragma unroll 8
        for (int kk = 0; kk < 32; ++kk) {
            float4 a0 = *(const float4*)&Xs[kk][tm*8];
            float4 a1 = *(const float4*)&Xs[kk][tm*8 + 4];
            float4 b0 = *(const float4*)&Ws[kk][tn*8];
            float4 b1 = *(const float4*)&Ws[kk][tn*8 + 4];
            float av[8] = {a0.x,a0.y,a0.z,a0.w,a1.x,a1.y,a1.z,a1.w};
            float bw[8] = {b0.x,b0.y,b0.z,b0.w,b1.x,b1.y,b1.z,b1.w};
            #pragma unroll
            for (int i = 0; i < 8; ++i)
                #pragma unroll
                for (int j = 0; j < 8; ++j)
                    acc[i][j] = fmaf(av[i], bw[j], acc[i][j]);
        }
    }

    float4 bb0 = *(const float4*)&bias[tn*8];
    float4 bb1 = *(const float4*)&bias[tn*8 + 4];
    float bb[8] = {bb0.x,bb0.y,bb0.z,bb0.w,bb1.x,bb1.y,bb1.z,bb1.w};
    #pragma unroll
    for (int i = 0; i < 8; ++i) {
        const size_t row = (size_t)(mb + tm*8 + i);
        float4 o0 = {acc[i][0]+bb[0], acc[i][1]+bb[1], acc[i][2]+bb[2], acc[i][3]+bb[3]};
        float4 o1 = {acc[i][4]+bb[4], acc[i][5]+bb[5], acc[i][6]+bb[6], acc[i][7]+bb[7]};
        *(float4*)&Y[row*256 + tn*8]     = o0;   // raw y (cached: read back below)
        *(float4*)&Y[row*256 + tn*8 + 4] = o1;
    }

    if (donorm) {
        __syncthreads();   // raw-y stores drained & visible block-wide (R15-proven)
        const int lane = t & 63;
        const int w    = t >> 6;
        #pragma unroll 1
        for (int rr = 0; rr < 16; ++rr) {
            const size_t row = (size_t)mb + rr*4 + w;
            // ---- verbatim rmsnorm_rows body (bit-identical sequence) ----
            float4 x = *(const float4*)&Y[row*256 + lane*4];
            float ssq = fmaf(x.x, x.x, fmaf(x.y, x.y, fmaf(x.z, x.z, x.w * x.w)));
            #pragma unroll
            for (int o = 1; o < 64; o <<= 1) ssq += __shfl_xor(ssq, o, 64);
            const float r = 1.0f / sqrtf(ssq * (1.0f/256.0f) + 1e-5f);
            float4 gg = *(const float4*)&g[lane*4];
            float y0 = (x.x*r)*gg.x, y1 = (x.y*r)*gg.y, y2 = (x.z*r)*gg.z, y3 = (x.w*r)*gg.w;
            float4 y = {y0, y1, y2, y3};
            *(float4*)&Y[row*256 + lane*4] = y;
            __hip_bfloat16 h0 = __float2bfloat16(y0), h1 = __float2bfloat16(y1);
            __hip_bfloat16 h2 = __float2bfloat16(y2), h3 = __float2bfloat16(y3);
            ushort4 p;
            p.x = *(unsigned short*)&h0; p.y = *(unsigned short*)&h1;
            p.z = *(unsigned short*)&h2; p.w = *(unsigned short*)&h3;
            ((ushort4*)Yb)[row*64 + lane] = p;
        }
    }
}

// ---------------- bf16 MFMA logits: Out[32768][4096] = fp32(clamp(Q @ K^T * 1/16)) ----
// Byte-identical to R14 (passed): m97 loop, both-sides LDS swizzle, LDS-bounce epilogue
// with NONTEMPORAL logits stores, Tmax emission, lb(256,4), XCD-chunked grid.
__device__ __forceinline__ void load_lds16(const void* g, void* l) {
    __builtin_amdgcn_global_load_lds((const __attribute__((address_space(1))) unsigned int*)g,
                                     (__attribute__((address_space(3))) unsigned int*)l, 16, 0, 0);
}

__global__ __launch_bounds__(256, 4)
void mfma_logits(const __hip_bfloat16* __restrict__ Qb, const __hip_bfloat16* __restrict__ Kb,
                 float* __restrict__ Out, float* __restrict__ Tmax)
{
    __shared__ __align__(16) char smem[33792];
    __hip_bfloat16* Asm = (__hip_bfloat16*)smem;            // [128 rows][64 k] bf16, 16KB
    __hip_bfloat16* Bsm = (__hip_bfloat16*)(smem + 16384);  // [128 rows][64 k] bf16, 16KB
    float*          Eps = (float*)smem;                     // [64 rows][128 cols] fp32, 32KB
    float*          Pmax = (float*)(smem + 32768);          // [128 rows][2 halves], 1KB

    const int t    = threadIdx.x;
    const int lane = t & 63;
    const int w    = t >> 6;
    const int wm = w >> 1, wn = w & 1;      // 2x2 wave grid of 64x64 quadrants

    const int bid = blockIdx.x;
    const int xcd = bid & 7;
    const int cid = bid >> 3;                // 0..1023
    const int mb  = (xcd * 32 + (cid & 31)) * 128;
    const int ctl = cid >> 5;                // col-tile 0..31
    const int nb  = ctl * 128;

    const int grow   = t >> 3;                       // + i*32 per issue
    const int gslot  = (t & 7) ^ ((t >> 3) & 7);
    const __hip_bfloat16* gA = Qb + (size_t)(mb + grow) * 256 + gslot * 8;
    const __hip_bfloat16* gB = Kb + (size_t)(nb + grow) * 256 + gslot * 8;
    __hip_bfloat16* lA = &Asm[w * 512];              // + i*2048 per issue (bf16 elems)
    __hip_bfloat16* lB = &Bsm[w * 512];

    const int fr = lane & 15;
    const int kq = lane >> 4;
    const int rswz = lane & 7;                       // row&7 for all our fragment rows
    const int ra0 = (wm * 64 + fr) * 64;             // A base elem offset (row*64)
    const int rb0 = (wn * 64 + fr) * 64;

    f32x4 acc[4][4];
    #pragma unroll
    for (int mi = 0; mi < 4; ++mi)
        #pragma unroll
        for (int ni = 0; ni < 4; ++ni) {
            acc[mi][ni][0] = 0.f; acc[mi][ni][1] = 0.f;
            acc[mi][ni][2] = 0.f; acc[mi][ni][3] = 0.f;
        }

    for (int ks = 0; ks < 4; ++ks) {
        const int k0 = ks * 64;
        #pragma unroll
        for (int i = 0; i < 4; ++i) {
            load_lds16(gA + (size_t)i * 32 * 256 + k0, lA + i * 2048);
            load_lds16(gB + (size_t)i * 32 * 256 + k0, lB + i * 2048);
        }
        __syncthreads();   // compiler drains vmcnt(0) before s_barrier [m97 evidence]

        #pragma unroll
        for (int kh = 0; kh < 2; ++kh) {            // ascending k == R4..R14 order
            bf16x8 af[4], bg[4];
            #pragma unroll
            for (int mi = 0; mi < 4; ++mi)
                af[mi] = *(const bf16x8*)&Asm[ra0 + mi*16*64 + (((kh<<2) + kq) ^ rswz) * 8];
            #pragma unroll
            for (int ni = 0; ni < 4; ++ni)
                bg[ni] = *(const bf16x8*)&Bsm[rb0 + ni*16*64 + (((kh<<2) + kq) ^ rswz) * 8];
            #pragma unroll
            for (int mi = 0; mi < 4; ++mi)
                #pragma unroll
                for (int ni = 0; ni < 4; ++ni)
                    acc[mi][ni] = __builtin_amdgcn_mfma_f32_16x16x32_bf16(
                        af[mi], bg[ni], acc[mi][ni], 0, 0, 0);
        }
        __syncthreads();   // LDS reads done before next K-step overwrites / epilogue
    }

    // ---- per-row partial maxima from acc regs (row = wm*64+mi*16+(lane>>4)*4+j) ----
    #pragma unroll
    for (int mi = 0; mi < 4; ++mi)
        #pragma unroll
        for (int j = 0; j < 4; ++j) {
            float mx = fmaxf(fmaxf(acc[mi][0][j], acc[mi][1][j]),
                             fmaxf(acc[mi][2][j], acc[mi][3][j]));
            #pragma unroll
            for (int o = 1; o < 16; o <<= 1) mx = fmaxf(mx, __shfl_xor(mx, o, 64));
            if ((lane & 15) == 0)
                Pmax[(wm*64 + mi*16 + (lane>>4)*4 + j)*2 + wn] = mx;
        }

    // ---- epilogue: LDS bounce -> coalesced full-row dwordx4 NONTEMPORAL stores ----
    const int cr = (lane >> 4) * 4;
    const int cc = lane & 15;
    #pragma unroll
    for (int c = 0; c < 2; ++c) {                    // chunk: rows [c*64, c*64+64)
        if (wm == c) {
            #pragma unroll
            for (int mi = 0; mi < 4; ++mi)
                #pragma unroll
                for (int ni = 0; ni < 4; ++ni) {
                    const int lrow = mi*16 + cr;                  // 0..63 within chunk
                    const int lcol = wn*64 + ni*16 + cc;          // 0..127
                    #pragma unroll
                    for (int j = 0; j < 4; ++j) {
                        float v = acc[mi][ni][j] * 0.0625f;
                        v = fminf(fmaxf(v, -16.0f), 16.0f);
                        Eps[(lrow + j) * 128 + lcol] = v;
                    }
                }
        }
        __syncthreads();   // bounce tile (and, first pass, Pmax) complete
        #pragma unroll
        for (int it = 0; it < 8; ++it) {
            const int p   = it * 1024 + t * 4;       // linear word index in [64][128]
            const int row = p >> 7;
            const int col = p & 127;
            float4 v = *(const float4*)&Eps[p];
            nt_store4(v, &Out[(size_t)(mb + c*64 + row) * 4096 + nb + col]);
        }
        __syncthreads();   // chunk read done before next chunk overwrites
    }

    // ---- Tmax: max is monotone under clamp(0.0625*x) -> equals max of stored values.
    if (t < 128) {
        float raw = fmaxf(Pmax[t*2], Pmax[t*2 + 1]);
        float v = raw * 0.0625f;
        v = fminf(fmaxf(v, -16.0f), 16.0f);
        Tmax[(size_t)(mb + t) * 32 + ctl] = v;
    }
}

// ---------------- FROZEN canonical fp32 dot (argmax determinism anchor) ----------------
// DO NOT change the summation structure. R3..R15 PASSED with this exact sequence.
__device__ __forceinline__ float dot256_f32(const float* __restrict__ a, const float* __restrict__ b)
{
    float s0 = 0.f, s1 = 0.f, s2 = 0.f, s3 = 0.f;
    #pragma unroll 8
    for (int j = 0; j < 64; ++j) {
        float4 x = ((const float4*)a)[j];
        float4 y = ((const float4*)b)[j];
        s0 = fmaf(x.x, y.x, s0);
        s1 = fmaf(x.y, y.y, s1);
        s2 = fmaf(x.z, y.z, s2);
        s3 = fmaf(x.w, y.w, s3);
    }
    return (s0 + s1) + (s2 + s3);
}

// ---------------- refine (fast): Tmax-pruned candidate scan + frozen dots ----------------
// Byte-identical to R14 (passed): nt stores for idx/z_q/z_q_2; Qf aliases Zq (reads
// complete before the aliased overwrite via the bi data dependence).
__global__ __launch_bounds__(256)
void refine_argmax_fast(const float* __restrict__ L, const float* __restrict__ Tmax,
                        const float* __restrict__ Qf, const float* __restrict__ Kf,
                        const float* __restrict__ Vf, float* __restrict__ OutIdx,
                        float* __restrict__ Zq, float* __restrict__ Zq2)
{
    __shared__ int cnt[4];
    __shared__ int list[4][256];
    const int lane = threadIdx.x & 63;
    const int w    = threadIdx.x >> 6;
    const size_t row = (size_t)blockIdx.x * 4 + w;

    // phase 1: row max from 32 tile maxima
    float tm = (lane < 32) ? Tmax[row * 32 + lane] : -INFINITY;
    float gmax = tm;
    #pragma unroll
    for (int o = 1; o < 64; o <<= 1) gmax = fmaxf(gmax, __shfl_xor(gmax, o, 64));
    const float thr = gmax - 0.5f;

    if (lane == 0) cnt[w] = 0;
    __syncthreads();   // unconditional

    // phase 2: scan ONLY candidate tiles (512B each, float2/lane coalesced)
    for (int tile = 0; tile < 32; ++tile) {
        const float tmt = __shfl(tm, tile, 64);
        if (tmt >= thr) {
            const float2 v2 = *(const float2*)&L[row * 4096 + tile * 128 + lane * 2];
            if (v2.x >= thr) {
                int slot = atomicAdd(&cnt[w], 1);
                if (slot < 256) list[w][slot] = tile*128 + lane*2;
            }
            if (v2.y >= thr) {
                int slot = atomicAdd(&cnt[w], 1);
                if (slot < 256) list[w][slot] = tile*128 + lane*2 + 1;
            }
        }
    }
    __syncthreads();   // unconditional

    // phase 3: one candidate per lane, all dots in ONE exec pass
    int m = cnt[w]; if (m > 256) m = 256;
    float bv = -INFINITY;
    int   bi = 0x7fffffff;
    const float* qrow = Qf + row * 256;
    for (int base = 0; base < m; base += 64) {
        const int ci = base + lane;
        if (ci < m) {
            const int c = list[w][ci];
            float rv = dot256_f32(qrow, Kf + (size_t)c * 256) * 0.0625f;
            if (rv > bv || (rv == bv && c < bi)) { bv = rv; bi = c; }
        }
    }
    #pragma unroll
    for (int o = 1; o < 64; o <<= 1) {
        float ov = __shfl_xor(bv, o, 64);
        int   oi = __shfl_xor(bi, o, 64);
        if (ov > bv || (ov == bv && oi < bi)) { bv = ov; bi = oi; }
    }

    if (bi < 0) bi = 0;
    if (bi > 4095) bi = 4095;

    if (lane == 0) __builtin_nontemporal_store((float)bi, &OutIdx[row]);

    float4 vv = ((const float4*)(Vf + (size_t)bi * 256))[lane];
    nt_store4(vv, (float*)&((float4*)Zq)[row*64 + lane]);
    nt_store4(vv, (float*)&((float4*)Zq2)[row*64 + lane]);
}

extern "C" void kernel_launch(void* const* d_in, const int* in_sizes, int n_in,
                              void* d_out, int out_size, void* d_ws, size_t ws_size,
                              hipStream_t stream)
{
    (void)in_sizes; (void)n_in; (void)out_size;
    const float* hs = (const float*)d_in[0];
    const float* cb = (const float*)d_in[1];
    const float* wq = (const float*)d_in[2];
    const float* bq = (const float*)d_in[3];
    const float* wk = (const float*)d_in[4];
    const float* bk = (const float*)d_in[5];
    const float* wv = (const float*)d_in[6];
    const float* bv = (const float*)d_in[7];
    const float* gq = (const float*)d_in[8];
    const float* gk = (const float*)d_in[9];
    float* out = (float*)d_out;   // fp32: reference outputs are fp32/int32

    if (ws_size < 31457280u) return;  // need 30MB scratch

    // d_out layout (floats): logits @0 [32768*4096], idx @134217728 [32768],
    // z_q @134250496 [32768*256], z_q_2 @142639104 [32768*256].
    float* qf = out + 134250496ull;   // q lives in the z_q region until the FINAL refine store

    char* ws = (char*)d_ws;
    float* kf = (float*)ws;                                   //  4 MB: k raw -> k_norm (in place)
    float* vf = (float*)(ws + 4194304);                       //  4 MB: v
    __hip_bfloat16* qb = (__hip_bfloat16*)(ws + 8388608);     // 16 MB: q_norm bf16
    __hip_bfloat16* kb = (__hip_bfloat16*)(ws + 25165824);    //  2 MB: k_norm bf16
    float* tmax = (float*)(ws + 27262976);                    //  4 MB: per-tile row max

    gemm3_norm<<<640, 256, 0, stream>>>(hs, cb, wq, bq, wk, bk, wv, bv, gq, gk,
                                        qf, kf, vf, qb, kb);
    mfma_logits<<<8192, 256, 0, stream>>>(qb, kb, out, tmax);
    refine_argmax_fast<<<8192, 256, 0, stream>>>(out, tmax, qf, kf, vf,
        out + 134217728ull,   // idx
        out + 134250496ull,   // z_q   (aliases qf by design)
        out + 142639104ull);  // z_q_2
}